// Round 2
// baseline (310.356 us; speedup 1.0000x reference)
//
#include <hip/hip_runtime.h>
#include <hip/hip_bf16.h>

#define DEPTH    8
#define NIN      128
#define NCLS     10
#define NNODES   255
#define NLEAVES  256
#define TSAMP    65536

// dynamic LDS layout (floats):
//   Wl   [0, 32640)          255 x 128
//   bl   [32640, +256)
//   betal[32896, +256)
//   rl   [33152, +256)
//   red  [33408, +8)
#define LDS_FLOATS (NNODES * NIN + 256 + 256 + 256 + 8)

extern "C" __global__ void __launch_bounds__(256, 1)
sdt_main(const float* __restrict__ x, const float* __restrict__ W,
         const float* __restrict__ b, const float* __restrict__ beta,
         const float* __restrict__ leaf_dist, const float* __restrict__ class_reward,
         float* __restrict__ out) {
    extern __shared__ float smem[];
    float* Wl    = smem;
    float* bl    = smem + NNODES * NIN;
    float* betal = smem + NNODES * NIN + 256;
    float* rl    = smem + NNODES * NIN + 512;
    float* red   = smem + NNODES * NIN + 768;

    const int tid = threadIdx.x;

    // ---- stage W, b, beta into LDS; compute r[leaf] redundantly per block ----
    {
        const float4* Wg  = (const float4*)W;
        float4*       Wl4 = (float4*)Wl;
        for (int i = tid; i < (NNODES * NIN) / 4; i += 256) Wl4[i] = Wg[i];
        if (tid < NNODES) { bl[tid] = b[tid]; betal[tid] = beta[tid]; }
        if (tid < NLEAVES) {
            float v[NCLS];
            float mx = -1e30f;
            #pragma unroll
            for (int c = 0; c < NCLS; ++c) { v[c] = leaf_dist[tid * NCLS + c]; mx = fmaxf(mx, v[c]); }
            float s = 0.f, d = 0.f;
            #pragma unroll
            for (int c = 0; c < NCLS; ++c) {
                float e = __expf(v[c] - mx);
                s += e;
                d += e * class_reward[c];
            }
            rl[tid] = __fdividef(d, s);
        }
    }
    __syncthreads();

    // ---- load this thread's x row into registers (32 x float4) ----
    const int samp = blockIdx.x * 256 + tid;
    float4 xr[32];
    {
        const float4* xg = (const float4*)(x + samp * NIN);
        #pragma unroll
        for (int i = 0; i < 32; ++i) xr[i] = xg[i];
    }

    // sigmoid(beta[node] * (x . W[node] + b[node])), W from LDS (uniform broadcast)
    auto SIG = [&](int node) -> float {
        const float* wrow = Wl + (node << 7);
        float a0 = 0.f, a1 = 0.f, a2 = 0.f, a3 = 0.f;
        #pragma unroll
        for (int i = 0; i < 32; ++i) {
            float4 wv = ((const float4*)wrow)[i];
            a0 = fmaf(xr[i].x, wv.x, a0);
            a1 = fmaf(xr[i].y, wv.y, a1);
            a2 = fmaf(xr[i].z, wv.z, a2);
            a3 = fmaf(xr[i].w, wv.w, a3);
        }
        float t = betal[node] * (((a0 + a1) + (a2 + a3)) + bl[node]);
        return __fdividef(1.f, 1.f + __expf(-t));
    };

    // ---- DFS over leaves with register prefix products ----
    // depth d node index: (1<<d)-1 + (L >> (8-d)); left child factor p, right 1-p
    float p0, p1, p2, p3, p4, p5, p6;
    float f0, f1, f2, f3, f4, f5, f6;
    float acc;

    p0 = SIG(0);   f0 = p0;
    p1 = SIG(1);   f1 = f0 * p1;
    p2 = SIG(3);   f2 = f1 * p2;
    p3 = SIG(7);   f3 = f2 * p3;
    p4 = SIG(15);  f4 = f3 * p4;
    p5 = SIG(31);  f5 = f4 * p5;
    p6 = SIG(63);  f6 = f5 * p6;
    {
        float p7 = SIG(127);
        acc = f6 * (p7 * rl[0] + (1.f - p7) * rl[1]);
    }

    for (int L = 2; L < 256; L += 2) {
        const int z = __builtin_ctz((unsigned)L);  // uniform across all lanes
        switch (z) {
            case 1:  f6 = f5 * (1.f - p6); break;
            case 2:  f5 = f4 * (1.f - p5); break;
            case 3:  f4 = f3 * (1.f - p4); break;
            case 4:  f3 = f2 * (1.f - p3); break;
            case 5:  f2 = f1 * (1.f - p2); break;
            case 6:  f1 = f0 * (1.f - p1); break;
            default: f0 = 1.f - p0;        break;  // z == 7 (L == 128)
        }
        if (z >= 7) { p1 = SIG(1   + (L >> 7)); f1 = f0 * p1; }
        if (z >= 6) { p2 = SIG(3   + (L >> 6)); f2 = f1 * p2; }
        if (z >= 5) { p3 = SIG(7   + (L >> 5)); f3 = f2 * p3; }
        if (z >= 4) { p4 = SIG(15  + (L >> 4)); f4 = f3 * p4; }
        if (z >= 3) { p5 = SIG(31  + (L >> 3)); f5 = f4 * p5; }
        if (z >= 2) { p6 = SIG(63  + (L >> 2)); f6 = f5 * p6; }
        float p7 = SIG(127 + (L >> 1));
        acc += f6 * (p7 * rl[L] + (1.f - p7) * rl[L + 1]);
    }

    // ---- block reduction -> one atomicAdd per block ----
    #pragma unroll
    for (int off = 32; off > 0; off >>= 1) acc += __shfl_down(acc, off);
    const int lane = tid & 63, wid = tid >> 6;
    if (lane == 0) red[wid] = acc;
    __syncthreads();
    if (tid == 0) atomicAdd(out, (red[0] + red[1]) + (red[2] + red[3]));
}

extern "C" void kernel_launch(void* const* d_in, const int* in_sizes, int n_in,
                              void* d_out, int out_size, void* d_ws, size_t ws_size,
                              hipStream_t stream) {
    const float* x            = (const float*)d_in[0];
    const float* W            = (const float*)d_in[1];
    const float* b            = (const float*)d_in[2];
    const float* beta         = (const float*)d_in[3];
    const float* leaf_dist    = (const float*)d_in[4];
    const float* class_reward = (const float*)d_in[5];
    float* out = (float*)d_out;

    hipMemsetAsync(d_out, 0, sizeof(float), stream);

    const size_t lds_bytes = LDS_FLOATS * sizeof(float);
    hipFuncSetAttribute(reinterpret_cast<const void*>(sdt_main),
                        hipFuncAttributeMaxDynamicSharedMemorySize, (int)lds_bytes);

    sdt_main<<<TSAMP / 256, 256, lds_bytes, stream>>>(x, W, b, beta, leaf_dist,
                                                      class_reward, out);
}

// Round 4
// 132.672 us; speedup vs baseline: 2.3393x; 2.3393x over previous
//
#include <hip/hip_runtime.h>
#include <hip/hip_bf16.h>

#define NIN      128
#define NCLS     10
#define NNODES   255
#define NLEAVES  256
#define TSAMP    65536

#define MBLK     64        // samples per block
#define PITCH    68        // logit LDS row pitch in floats ([node][sample]); 68%32=4 -> conflict-free per-lane reads, 16B-aligned frag writes
#define NBLOCKS  (TSAMP / MBLK)

typedef short bf16x8 __attribute__((ext_vector_type(8)));
typedef float f32x4  __attribute__((ext_vector_type(4)));

// dynamic LDS (floats): logits[256][PITCH] | rl[256] | bl[256] | betal[256] | red[8]
#define LDS_FLOATS (256 * PITCH + 256 + 256 + 256 + 8)

__device__ __forceinline__ short f2b(float f) {
    return __builtin_bit_cast(short, __float2bfloat16(f));   // RNE hw cvt
}
__device__ __forceinline__ bf16x8 mk8(float4 a, float4 b) {
    bf16x8 r;
    r[0] = f2b(a.x); r[1] = f2b(a.y); r[2] = f2b(a.z); r[3] = f2b(a.w);
    r[4] = f2b(b.x); r[5] = f2b(b.y); r[6] = f2b(b.z); r[7] = f2b(b.w);
    return r;
}

extern "C" __global__ void __launch_bounds__(256, 1)
sdt_mfma(const float* __restrict__ x, const float* __restrict__ W,
         const float* __restrict__ b, const float* __restrict__ beta,
         const float* __restrict__ leaf_dist, const float* __restrict__ cr,
         float* __restrict__ out) {
    extern __shared__ float smem[];
    float* Lg    = smem;                    // [256][PITCH] logits, node-major
    float* rl    = smem + 256 * PITCH;      // [256] leaf reward
    float* bl    = rl + 256;                // [256] bias
    float* betal = bl + 256;                // [256] beta
    float* red   = betal + 256;             // [8] block reduce

    const int tid  = threadIdx.x;
    const int lane = tid & 63;
    const int w    = tid >> 6;              // wave 0..3

    // ---- stage b, beta; compute r[leaf] (one leaf per thread) ----
    if (tid < NNODES) { bl[tid] = b[tid]; betal[tid] = beta[tid]; }
    {
        float v[NCLS]; float mx = -1e30f;
        #pragma unroll
        for (int c = 0; c < NCLS; ++c) { v[c] = leaf_dist[tid * NCLS + c]; mx = fmaxf(mx, v[c]); }
        float s = 0.f, d = 0.f;
        #pragma unroll
        for (int c = 0; c < NCLS; ++c) { float e = __expf(v[c] - mx); s += e; d += e * cr[c]; }
        rl[tid] = __fdividef(d, s);
    }

    // ---- GEMM: logits[64 samples][256 nodes], bf16 MFMA 16x16x32 ----
    // wave w owns node-chunk n0 = w*64 (4 N-frags), all 64 samples (4 M-frags)
    const int r16 = lane & 15;              // fragment row/col index
    const int kg  = lane >> 4;              // k-group 0..3 (8 contiguous k each)
    const int m0  = blockIdx.x * MBLK;
    const int n0  = w * 64;

    f32x4 acc[4][4];
    #pragma unroll
    for (int i = 0; i < 4; ++i) {
        #pragma unroll
        for (int j = 0; j < 4; ++j) acc[i][j] = (f32x4){0.f, 0.f, 0.f, 0.f};
    }

    // A: lane holds x[m0 + mf*16 + r16][ks*32 + kg*8 + 0..7]
    const float4* ap = (const float4*)(x + (size_t)(m0 + r16) * NIN + kg * 8);
    // B: lane holds W[n0 + nf*16 + r16][ks*32 + kg*8 + 0..7]  (B[k][n] = W[n][k])
    const float4* bp0; const float4* bp1; const float4* bp2; const float4* bp3;
    {
        int nA = n0 + 0  + r16; if (nA > 254) nA = 254;
        int nB = n0 + 16 + r16; if (nB > 254) nB = 254;
        int nC = n0 + 32 + r16; if (nC > 254) nC = 254;
        int nD = n0 + 48 + r16; if (nD > 254) nD = 254;   // pad col 255 clamped
        bp0 = (const float4*)(W + (size_t)nA * NIN + kg * 8);
        bp1 = (const float4*)(W + (size_t)nB * NIN + kg * 8);
        bp2 = (const float4*)(W + (size_t)nC * NIN + kg * 8);
        bp3 = (const float4*)(W + (size_t)nD * NIN + kg * 8);
    }

    #pragma unroll
    for (int ks = 0; ks < 4; ++ks) {
        bf16x8 af[4], bfr[4];
        #pragma unroll
        for (int mf = 0; mf < 4; ++mf)
            af[mf] = mk8(ap[mf * 512 + ks * 8], ap[mf * 512 + ks * 8 + 1]);  // 512 float4 = 16 rows
        bfr[0] = mk8(bp0[ks * 8], bp0[ks * 8 + 1]);
        bfr[1] = mk8(bp1[ks * 8], bp1[ks * 8 + 1]);
        bfr[2] = mk8(bp2[ks * 8], bp2[ks * 8 + 1]);
        bfr[3] = mk8(bp3[ks * 8], bp3[ks * 8 + 1]);
        #pragma unroll
        for (int mf = 0; mf < 4; ++mf) {
            #pragma unroll
            for (int nf = 0; nf < 4; ++nf)
                acc[mf][nf] = __builtin_amdgcn_mfma_f32_16x16x32_bf16(
                    af[mf], bfr[nf], acc[mf][nf], 0, 0, 0);
        }
    }

    // C/D layout: col(N=node) = lane&15, row(M=sample) = kg*4 + reg  -> 4 regs are
    // 4 consecutive samples => contiguous float4 in [node][sample] LDS
    #pragma unroll
    for (int mf = 0; mf < 4; ++mf) {
        #pragma unroll
        for (int nf = 0; nf < 4; ++nf) {
            const int node = n0 + nf * 16 + r16;
            const int sl   = mf * 16 + kg * 4;
            *(f32x4*)&Lg[node * PITCH + sl] = acc[mf][nf];
        }
    }
    __syncthreads();

    // ---- tree phase: thread = (sample = lane, leaf-quarter = wave) ----
    const int s = lane;
    const int g = w;                       // leaf range [g*64, g*64+64)

    auto PV = [&](int node) -> float {     // p = sigmoid(beta*(logit+b))
        float t = betal[node] * (Lg[node * PITCH + s] + bl[node]);
        return __fdividef(1.f, 1.f + __expf(-t));
    };

    // prefix: levels 0,1 (leaf bits b0 = g>>1, b1 = g&1; bit=0 -> p, bit=1 -> 1-p)
    float f_pre;
    {
        float pr  = PV(0);
        f_pre = (g & 2) ? (1.f - pr) : pr;
        float p1v = PV(1 + (g >> 1));
        f_pre *= (g & 1) ? (1.f - p1v) : p1v;
    }

    // DFS over the depth-6 subtree rooted at node 3+g (64 leaves)
    float q0, q1, q2, q3, q4, F0, F1, F2, F3, F4, accv;
    q0 = PV(3 + g);            F0 = f_pre * q0;
    q1 = PV(7 + 2 * g);        F1 = F0 * q1;
    q2 = PV(15 + 4 * g);       F2 = F1 * q2;
    q3 = PV(31 + 8 * g);       F3 = F2 * q3;
    q4 = PV(63 + 16 * g);      F4 = F3 * q4;
    {
        float p7 = PV(127 + 32 * g);
        accv = F4 * (p7 * rl[g * 64] + (1.f - p7) * rl[g * 64 + 1]);
    }
    for (int LL = 2; LL < 64; LL += 2) {
        const int z = __builtin_ctz((unsigned)LL);   // 1..5, uniform
        switch (z) {
            case 1:  F4 = F3 * (1.f - q4); break;
            case 2:  F3 = F2 * (1.f - q3); break;
            case 3:  F2 = F1 * (1.f - q2); break;
            case 4:  F1 = F0 * (1.f - q1); break;
            default: F0 = f_pre * (1.f - q0); break;  // z==5 (LL==32)
        }
        if (z >= 5) { q1 = PV(7  + 2 * g  + (LL >> 5)); F1 = F0 * q1; }
        if (z >= 4) { q2 = PV(15 + 4 * g  + (LL >> 4)); F2 = F1 * q2; }
        if (z >= 3) { q3 = PV(31 + 8 * g  + (LL >> 3)); F3 = F2 * q3; }
        if (z >= 2) { q4 = PV(63 + 16 * g + (LL >> 2)); F4 = F3 * q4; }
        float p7 = PV(127 + 32 * g + (LL >> 1));
        accv += F4 * (p7 * rl[g * 64 + LL] + (1.f - p7) * rl[g * 64 + LL + 1]);
    }

    // ---- reduce: wave shuffle -> LDS -> one atomicAdd per block ----
    #pragma unroll
    for (int off = 32; off > 0; off >>= 1) accv += __shfl_down(accv, off);
    if (lane == 0) red[w] = accv;
    __syncthreads();
    if (tid == 0) atomicAdd(out, (red[0] + red[1]) + (red[2] + red[3]));
}

extern "C" void kernel_launch(void* const* d_in, const int* in_sizes, int n_in,
                              void* d_out, int out_size, void* d_ws, size_t ws_size,
                              hipStream_t stream) {
    const float* x            = (const float*)d_in[0];
    const float* W            = (const float*)d_in[1];
    const float* b            = (const float*)d_in[2];
    const float* beta         = (const float*)d_in[3];
    const float* leaf_dist    = (const float*)d_in[4];
    const float* class_reward = (const float*)d_in[5];
    float* out = (float*)d_out;

    hipMemsetAsync(d_out, 0, sizeof(float), stream);

    const size_t lds_bytes = LDS_FLOATS * sizeof(float);
    hipFuncSetAttribute(reinterpret_cast<const void*>(sdt_mfma),
                        hipFuncAttributeMaxDynamicSharedMemorySize, (int)lds_bytes);

    sdt_mfma<<<NBLOCKS, 256, lds_bytes, stream>>>(x, W, b, beta, leaf_dist,
                                                  class_reward, out);
}

// Round 5
// 118.555 us; speedup vs baseline: 2.6178x; 1.1191x over previous
//
#include <hip/hip_runtime.h>
#include <hip/hip_bf16.h>

#define NIN      128
#define NCLS     10
#define NNODES   255
#define TSAMP    65536

#define MBLK     64                 // samples per block
#define NBLOCKS  (TSAMP / MBLK)
#define LPITCH   72                 // Lg row pitch in bf16 elems (144 B)

typedef short bf16x8 __attribute__((ext_vector_type(8)));
typedef short short4v __attribute__((ext_vector_type(4)));
typedef float f32x4  __attribute__((ext_vector_type(4)));

// d_ws layout (bytes):
//   [0,     65280)  Wbf  : bf16 beta-scaled W, row-major 255x128
//   [65280, 66304)  bb   : f32[256] = beta*b   (index 255 unused)
//   [66304, 66816)  rd   : f32[128] = r[2t] - r[2t+1]
//   [66816, 67328)  r1   : f32[128] = r[2t+1]
#define WS_BB  65280
#define WS_RD  66304
#define WS_R1  66816

__device__ __forceinline__ short f2b(float f) {
    return __builtin_bit_cast(short, __float2bfloat16(f));   // RNE hw cvt
}
__device__ __forceinline__ float b2f(short h) {
    return __builtin_bit_cast(float, ((unsigned)(unsigned short)h) << 16);
}
__device__ __forceinline__ bf16x8 mk8(float4 a, float4 b) {
    bf16x8 r;
    r[0] = f2b(a.x); r[1] = f2b(a.y); r[2] = f2b(a.z); r[3] = f2b(a.w);
    r[4] = f2b(b.x); r[5] = f2b(b.y); r[6] = f2b(b.z); r[7] = f2b(b.w);
    return r;
}

// ---------------- pre-kernel: fold beta into W (bf16), b'=beta*b, leaf reward pairs ----
extern "C" __global__ void __launch_bounds__(128)
sdt_prep(const float* __restrict__ W, const float* __restrict__ b,
         const float* __restrict__ beta, const float* __restrict__ leaf_dist,
         const float* __restrict__ cr, char* __restrict__ ws) {
    short* Wbf = (short*)ws;
    float* bb  = (float*)(ws + WS_BB);
    float* rd  = (float*)(ws + WS_RD);
    float* r1  = (float*)(ws + WS_R1);
    const int n = blockIdx.x;       // 0..255
    const int t = threadIdx.x;      // 0..127
    if (n < NNODES) {
        const float be = beta[n];
        Wbf[n * NIN + t] = f2b(W[n * NIN + t] * be);
        if (t == 0) bb[n] = be * b[n];
    } else {
        // block 255: reward for leaf pair (2t, 2t+1)
        float rv[2];
        #pragma unroll
        for (int h = 0; h < 2; ++h) {
            const float* ld = leaf_dist + (size_t)(2 * t + h) * NCLS;
            float mx = -1e30f;
            float v[NCLS];
            #pragma unroll
            for (int c = 0; c < NCLS; ++c) { v[c] = ld[c]; mx = fmaxf(mx, v[c]); }
            float s = 0.f, d = 0.f;
            #pragma unroll
            for (int c = 0; c < NCLS; ++c) { float e = __expf(v[c] - mx); s += e; d += e * cr[c]; }
            rv[h] = __fdividef(d, s);
        }
        rd[t] = rv[0] - rv[1];
        r1[t] = rv[1];
    }
}

// ---------------- main kernel ----------------
extern "C" __global__ void __launch_bounds__(256, 4)
sdt_main(const float* __restrict__ x, const char* __restrict__ ws,
         float* __restrict__ out) {
    __shared__ short Lg[256 * LPITCH];   // beta-scaled logits, [node][sample] bf16
    __shared__ float bbS[256];
    __shared__ float rdS[128];
    __shared__ float r1S[128];
    __shared__ float v2S[4 * 64];
    __shared__ float red[8];

    const short* Wbf  = (const short*)ws;
    const float* g_bb = (const float*)(ws + WS_BB);
    const float* g_rd = (const float*)(ws + WS_RD);
    const float* g_r1 = (const float*)(ws + WS_R1);

    const int tid  = threadIdx.x;
    const int lane = tid & 63;
    const int w    = tid >> 6;

    // ---- stage small tables ----
    bbS[tid] = (tid < NNODES) ? g_bb[tid] : 0.f;
    if (tid < 128) { rdS[tid] = g_rd[tid]; r1S[tid] = g_r1[tid]; }

    // ---- GEMM: beta-scaled logits for 64 samples x 256 nodes (bf16 MFMA 16x16x32) ----
    const int r16 = lane & 15;
    const int kg  = lane >> 4;
    const int m0  = blockIdx.x * MBLK;
    const int n0  = w * 64;

    f32x4 acc[4][4];
    #pragma unroll
    for (int i = 0; i < 4; ++i)
        #pragma unroll
        for (int j = 0; j < 4; ++j) acc[i][j] = (f32x4){0.f, 0.f, 0.f, 0.f};

    const float4* ap = (const float4*)(x + (size_t)(m0 + r16) * NIN + kg * 8);
    int nidx[4];
    #pragma unroll
    for (int nf = 0; nf < 4; ++nf) {
        int nn = n0 + nf * 16 + r16;
        nidx[nf] = (nn > 254) ? 254 : nn;   // clamp: duplicate write of identical data
    }

    #pragma unroll
    for (int ks = 0; ks < 4; ++ks) {
        bf16x8 af[4], bfr[4];
        #pragma unroll
        for (int mf = 0; mf < 4; ++mf)
            af[mf] = mk8(ap[mf * 512 + ks * 8], ap[mf * 512 + ks * 8 + 1]);
        #pragma unroll
        for (int nf = 0; nf < 4; ++nf)
            bfr[nf] = *(const bf16x8*)(Wbf + nidx[nf] * NIN + ks * 32 + kg * 8);
        #pragma unroll
        for (int mf = 0; mf < 4; ++mf)
            #pragma unroll
            for (int nf = 0; nf < 4; ++nf)
                acc[mf][nf] = __builtin_amdgcn_mfma_f32_16x16x32_bf16(
                    af[mf], bfr[nf], acc[mf][nf], 0, 0, 0);
    }

    // C/D: col(node) = lane&15, row(sample) = kg*4 + reg -> 4 consecutive samples
    #pragma unroll
    for (int mf = 0; mf < 4; ++mf) {
        #pragma unroll
        for (int nf = 0; nf < 4; ++nf) {
            const int node = n0 + nf * 16 + r16;
            const int nd   = (node > 254) ? 254 : node;
            const int sl   = mf * 16 + kg * 4;
            short4v hv;
            hv[0] = f2b(acc[mf][nf][0]); hv[1] = f2b(acc[mf][nf][1]);
            hv[2] = f2b(acc[mf][nf][2]); hv[3] = f2b(acc[mf][nf][3]);
            *(short4v*)&Lg[nd * LPITCH + sl] = hv;
        }
    }
    __syncthreads();

    // ---- tree phase: bottom-up level sweep; thread = (sample=lane, quarter=wave) ----
    const int s = lane;
    const int g = w;

    auto SIG = [&](int node, int smp) -> float {   // p = sigmoid(logit' + b')
        float t = b2f(Lg[node * LPITCH + smp]) + bbS[node];
        return __fdividef(1.f, 1.f + __expf(-t));
    };

    float v7[32];
    #pragma unroll
    for (int i = 0; i < 32; ++i) {
        float p = SIG(127 + 32 * g + i, s);
        v7[i] = fmaf(p, rdS[32 * g + i], r1S[32 * g + i]);
    }
    float v6[16];
    #pragma unroll
    for (int i = 0; i < 16; ++i) {
        float p = SIG(63 + 16 * g + i, s);
        v6[i] = fmaf(p, v7[2 * i] - v7[2 * i + 1], v7[2 * i + 1]);
    }
    float v5[8];
    #pragma unroll
    for (int i = 0; i < 8; ++i) {
        float p = SIG(31 + 8 * g + i, s);
        v5[i] = fmaf(p, v6[2 * i] - v6[2 * i + 1], v6[2 * i + 1]);
    }
    float v4[4];
    #pragma unroll
    for (int i = 0; i < 4; ++i) {
        float p = SIG(15 + 4 * g + i, s);
        v4[i] = fmaf(p, v5[2 * i] - v5[2 * i + 1], v5[2 * i + 1]);
    }
    float v3[2];
    #pragma unroll
    for (int i = 0; i < 2; ++i) {
        float p = SIG(7 + 2 * g + i, s);
        v3[i] = fmaf(p, v4[2 * i] - v4[2 * i + 1], v4[2 * i + 1]);
    }
    {
        float p = SIG(3 + g, s);
        v2S[g * 64 + s] = fmaf(p, v3[0] - v3[1], v3[1]);
    }
    __syncthreads();

    // ---- final combine (wave 0) + block reduction ----
    if (tid < 64) {
        float p0 = SIG(0, tid);
        float p1 = SIG(1, tid);
        float p2 = SIG(2, tid);
        float L  = fmaf(p1, v2S[0 * 64 + tid] - v2S[1 * 64 + tid], v2S[1 * 64 + tid]);
        float R  = fmaf(p2, v2S[2 * 64 + tid] - v2S[3 * 64 + tid], v2S[3 * 64 + tid]);
        float val = fmaf(p0, L - R, R);
        #pragma unroll
        for (int off = 32; off > 0; off >>= 1) val += __shfl_down(val, off);
        if (tid == 0) atomicAdd(out, val);
    }
    (void)red;
}

extern "C" void kernel_launch(void* const* d_in, const int* in_sizes, int n_in,
                              void* d_out, int out_size, void* d_ws, size_t ws_size,
                              hipStream_t stream) {
    const float* x            = (const float*)d_in[0];
    const float* W            = (const float*)d_in[1];
    const float* b            = (const float*)d_in[2];
    const float* beta         = (const float*)d_in[3];
    const float* leaf_dist    = (const float*)d_in[4];
    const float* class_reward = (const float*)d_in[5];
    float* out = (float*)d_out;

    hipMemsetAsync(d_out, 0, sizeof(float), stream);

    sdt_prep<<<256, 128, 0, stream>>>(W, b, beta, leaf_dist, class_reward,
                                      (char*)d_ws);
    sdt_main<<<NBLOCKS, 256, 0, stream>>>(x, (const char*)d_ws, out);
}